// Round 10
// baseline (892.957 us; speedup 1.0000x reference)
//
#include <hip/hip_runtime.h>
#include <math.h>

// Model_39676907887961: out = dropout(softmax(x1@x2^T / x3)) @ x1 + x2
// B=2 H=16 S=2048 D=128. Round 16: r15 barrier-free structure + XCD-aware
// block swizzle (T1).
//   r15 post-mortem: direct global->VGPR K/V refetch went to HBM (FETCH
//   1.26 GB = 1024 blk x 1 MB; 3.67 TB/s, 46% peak) because same-bh blocks
//   were round-robined across XCDs -> no L2 reuse. Fix: remap blockIdx so all
//   32 qt-blocks of one bh share blk&7 (same XCD under round-robin): each
//   XCD hosts 4 bh = 4 MB K+V in its L2; tiles stream HBM->L2 once.
//   bh = (blk&7)*4 + ((blk>>3)&3), qt = blk>>5 (bijective, perf-only).
//   Everything else byte-identical to r15: no main-loop barriers, P same-wave
//   exchange in 8 KB LDS, direct epilogue store, tf-per-current-tile as
//   load-latency cover.
// Mask semantics (verified r9-r15): keep iff MSB(o0)==0 of
// threefry2x32(key=(0,42), ctr=(0,f)), f = row*2048 + t*64 + h2*16 + g*4 + i.

constexpr int Sc = 2048, Dc = 128;
constexpr int NT = 32;                     // 32 tiles of BK=64

typedef short bf16x8 __attribute__((ext_vector_type(8)));
typedef float f32x4 __attribute__((ext_vector_type(4)));
union U8 { uint4 u; bf16x8 v; };

__device__ __forceinline__ unsigned rotl(unsigned x, int r) {
  return __builtin_amdgcn_alignbit(x, x, 32 - r);   // rotl(x,r) = rotr(x,32-r)
}

// JAX Threefry-2x32, key=(0,42), ctr=(0,idx): o0 only (x1-tail dead-coded).
__device__ __forceinline__ unsigned tf_o0(unsigned x1) {
  const unsigned ks1 = 42u;
  const unsigned ks2 = 0x1BD11BDAu ^ 42u;  // ks0 = 0
  unsigned x0 = 0u; x1 += ks1;
#define TFR(r) { x0 += x1; x1 = rotl(x1, r); x1 ^= x0; }
  TFR(13) TFR(15) TFR(26) TFR(6)
  x0 += ks1; x1 += ks2 + 1u;
  TFR(17) TFR(29) TFR(16) TFR(24)
  x0 += ks2; x1 += 0u + 2u;
  TFR(13) TFR(15) TFR(26) TFR(6)
  x1 += ks1 + 3u;                          // x0 += ks0 (= 0)
  TFR(17) TFR(29) TFR(16) TFR(24)
  x0 += ks1; x1 += ks2 + 4u;
  TFR(13) TFR(15) TFR(26)
  x0 += x1;                                // final TFR(6): x1 update is dead
  x0 += ks2;                               // o0
#undef TFR
  return x0;
}

// keep iff MSB(o0)==0 -> full-width 0xFFFFFFFF / 0
__device__ __forceinline__ unsigned keepmask(unsigned idx) {
  return (unsigned)(((int)~tf_o0(idx)) >> 31);
}

// pack two f32 -> bf16 pair (round-half-up via +0x8000, then v_perm)
__device__ __forceinline__ unsigned pk2rn(float a, float b) {
  return __builtin_amdgcn_perm(__float_as_uint(b) + 0x8000u,
                               __float_as_uint(a) + 0x8000u, 0x07060302u);
}

// halfword-combine two full-width masks: lo16 from ma, hi16 from mb
__device__ __forceinline__ unsigned hw2(unsigned ma, unsigned mb) {
  return __builtin_amdgcn_perm(mb, ma, 0x05040100u);
}

// 8 halfword-pair keep-masks for one 64-key tile row-slice
__device__ __forceinline__ void masks8(unsigned ib, unsigned km[8]) {
#pragma unroll
  for (int h2 = 0; h2 < 4; ++h2) {
    unsigned a0 = keepmask(ib + h2 * 16 + 0), a1 = keepmask(ib + h2 * 16 + 1);
    unsigned a2 = keepmask(ib + h2 * 16 + 2), a3 = keepmask(ib + h2 * 16 + 3);
    km[h2 * 2 + 0] = hw2(a0, a1);
    km[h2 * 2 + 1] = hw2(a2, a3);
  }
}

// ---------------- pre-pass (r5, proven): fragment-linear bf16 images --------
// Per 32-key tile (tile index = bh*64 + tt):
//  K unit u = (mt*4+c)*64 + lane : K[mt*16+(lane&15)][c*32+(lane>>4)*8 .. +7]
//  V unit u = dt*64 + lane       : V[(lane>>4)*8+2p(+1)][dt*16+(lane&15)] pairs
__global__ __launch_bounds__(256)
void prepack(const float* __restrict__ x1, const float* __restrict__ x2,
             uint4* __restrict__ Kb, uint4* __restrict__ Vt) {
  __shared__ ushort Kl[32 * 136];
  __shared__ ushort Vl[32 * 136];
  const int tid = threadIdx.x;
  const size_t tile = blockIdx.x;            // 0..2047
  const float4* ks = (const float4*)(x2 + tile * 4096);
  const float4* vs = (const float4*)(x1 + tile * 4096);
#pragma unroll
  for (int it = 0; it < 4; ++it) {
    int f = it * 256 + tid;
    int row = f >> 5, c4 = f & 31;
    float4 kv = ks[f];
    float4 vv = vs[f];
    *(uint2*)&Kl[row * 136 + c4 * 4] = uint2{pk2rn(kv.x, kv.y), pk2rn(kv.z, kv.w)};
    *(uint2*)&Vl[row * 136 + c4 * 4] = uint2{pk2rn(vv.x, vv.y), pk2rn(vv.z, vv.w)};
  }
  __syncthreads();
#pragma unroll
  for (int it = 0; it < 2; ++it) {
    int u = it * 256 + tid;
    int lane = u & 63, grp = u >> 6;
    int mt = grp >> 2, c = grp & 3, m16 = lane & 15, g = lane >> 4;
    Kb[tile * 512 + u] = *(const uint4*)&Kl[(mt * 16 + m16) * 136 + c * 32 + g * 8];
  }
#pragma unroll
  for (int it = 0; it < 2; ++it) {
    int u = it * 256 + tid;
    int lane = u & 63, dt = u >> 6, m16 = lane & 15, g = lane >> 4;
    int d = dt * 16 + m16, k0 = g * 8;
    unsigned w[4];
#pragma unroll
    for (int p = 0; p < 4; ++p) {
      unsigned lo = Vl[(k0 + 2 * p) * 136 + d];
      unsigned hi = Vl[(k0 + 2 * p + 1) * 136 + d];
      w[p] = lo | (hi << 16);
    }
    Vt[tile * 512 + u] = uint4{w[0], w[1], w[2], w[3]};
  }
}

// ---------------- main kernel ----------------------------------------------
__global__ __launch_bounds__(256, 8)
void attn12(const uint4* __restrict__ Kb, const uint4* __restrict__ Vt,
            const float* __restrict__ x1, const float* __restrict__ x2,
            const float* __restrict__ x3, float* __restrict__ out) {
  __shared__ uint4 smemv[8192 / 16];         // 8 KiB: P region only
  char* smem = (char*)smemv;

  const int tid = threadIdx.x, wave = tid >> 6, lane = tid & 63;
  const int g = lane >> 4, q = lane & 15;
  // XCD-aware swizzle: all 32 qt-blocks of a bh share blk&7 -> same XCD
  // under round-robin placement; each XCD L2-caches 4 bh (4 MB K+V).
  const int blk = blockIdx.x;
  const int bh = (blk & 7) * 4 + ((blk >> 3) & 3);
  const int qt = blk >> 5;

  const float* X1 = x1 + (size_t)bh * (Sc * Dc);
  const float* X2 = x2 + (size_t)bh * (Sc * Dc);
  float* outp = out + (size_t)bh * (Sc * Dc);
  const float cl2 = (1.0f / x3[bh]) * 1.4426950408889634f;   // fold log2(e)

  const int qrow = qt * 64 + wave * 16 + q;
  const unsigned row_base = (unsigned)(bh * Sc + qrow) * (unsigned)Sc;
  char* prow = smem + wave * 2048 + q * 128;   // this lane's P row (64 keys)

  const size_t tg = (size_t)bh * 64;

  // Q B-frags: qf[c] = Q[qrow][c*32 + g*8 .. +7]
  bf16x8 qf[4];
  {
    const float4* qsrc = (const float4*)(X1 + (size_t)qrow * Dc);
#pragma unroll
    for (int c = 0; c < 4; ++c) {
      float4 f0 = qsrc[c * 8 + g * 2], f1 = qsrc[c * 8 + g * 2 + 1];
      U8 cv; cv.u = uint4{pk2rn(f0.x, f0.y), pk2rn(f0.z, f0.w),
                          pk2rn(f1.x, f1.y), pk2rn(f1.z, f1.w)};
      qf[c] = cv.v;
    }
  }

  f32x4 o[8];
#pragma unroll
  for (int i = 0; i < 8; ++i) o[i] = f32x4{0.f, 0.f, 0.f, 0.f};
  float l_run = 0.0f;

  for (int t = 0; t < NT; ++t) {
    const uint4* Kg = Kb + (tg + 2 * (size_t)t) * 512;   // subtiles 2t, 2t+1
    const uint4* Vg = Vt + (tg + 2 * (size_t)t) * 512;

    // ---- K fragments: direct global->VGPR (fragment-linear layout);
    //      same-XCD blocks share these lines via L2. ----
    U8 kf[16];
#pragma unroll
    for (int mc = 0; mc < 8; ++mc) kf[mc].u      = Kg[mc * 64 + lane];
#pragma unroll
    for (int mc = 0; mc < 8; ++mc) kf[8 + mc].u  = Kg[512 + mc * 64 + lane];

    // ---- threefry for THIS tile: pure VALU, covers the K load latency ----
    unsigned km[8];
    masks8(row_base + (unsigned)(t * 64) + (unsigned)(g * 4), km);

    // ---- S^T = K·Q^T : s[h2][reg] = score(key = h2*16 + g*4 + reg, col q) --
    f32x4 s0 = {}, s1 = {}, s2 = {}, s3 = {};
#pragma unroll
    for (int c = 0; c < 4; ++c) {
      s0 = __builtin_amdgcn_mfma_f32_16x16x32_bf16(kf[c].v,      qf[c], s0, 0, 0, 0);
      s1 = __builtin_amdgcn_mfma_f32_16x16x32_bf16(kf[4 + c].v,  qf[c], s1, 0, 0, 0);
      s2 = __builtin_amdgcn_mfma_f32_16x16x32_bf16(kf[8 + c].v,  qf[c], s2, 0, 0, 0);
      s3 = __builtin_amdgcn_mfma_f32_16x16x32_bf16(kf[12 + c].v, qf[c], s3, 0, 0, 0);
    }

    // ---- V fragments: issue now; softmax+pack covers their latency ----
    U8 vf0[8], vf1[8];
#pragma unroll
    for (int dt = 0; dt < 8; ++dt) {
      vf0[dt].u = Vg[dt * 64 + lane];
      vf1[dt].u = Vg[512 + dt * 64 + lane];
    }

    // ---- no-max softmax: p = 2^(s*cl2); l excludes dropout ----
    float pr[16];
    float ls = 0.0f;
#pragma unroll
    for (int i = 0; i < 4; ++i) { pr[i]      = __builtin_amdgcn_exp2f(s0[i] * cl2); ls += pr[i]; }
#pragma unroll
    for (int i = 0; i < 4; ++i) { pr[4 + i]  = __builtin_amdgcn_exp2f(s1[i] * cl2); ls += pr[4 + i]; }
#pragma unroll
    for (int i = 0; i < 4; ++i) { pr[8 + i]  = __builtin_amdgcn_exp2f(s2[i] * cl2); ls += pr[8 + i]; }
#pragma unroll
    for (int i = 0; i < 4; ++i) { pr[12 + i] = __builtin_amdgcn_exp2f(s3[i] * cl2); ls += pr[12 + i]; }
    ls += __shfl_xor(ls, 16);
    ls += __shfl_xor(ls, 32);
    l_run += ls;

    // ---- pack + mask + write P units (unit u = (h2>>1)*8+(h2&1)*4+g,
    //      4 bf16 keys each; XOR-swizzled by q, same-wave exchange, NO barrier)
#pragma unroll
    for (int h2 = 0; h2 < 4; ++h2) {
      unsigned w0 = pk2rn(pr[h2 * 4 + 0], pr[h2 * 4 + 1]) & km[h2 * 2 + 0];
      unsigned w1 = pk2rn(pr[h2 * 4 + 2], pr[h2 * 4 + 3]) & km[h2 * 2 + 1];
      int u = (h2 >> 1) * 8 + (h2 & 1) * 4 + g;
      *(uint2*)(prow + ((u ^ q) & 15) * 8) = uint2{w0, w1};
    }

    // ---- B-frags for PV from P rows (b64 pairs, swizzle-aware order) ----
    U8 bf0, bf1;
    {
      int u0 = 2 * g;            // kh = 0: keys g*8 .. +7
      uint2 lo0 = *(const uint2*)(prow + (((u0 + 0) ^ q) & 15) * 8);
      uint2 hi0 = *(const uint2*)(prow + (((u0 + 1) ^ q) & 15) * 8);
      bf0.u = uint4{lo0.x, lo0.y, hi0.x, hi0.y};
      int u1 = 8 + 2 * g;        // kh = 1: keys 32 + g*8 .. +7
      uint2 lo1 = *(const uint2*)(prow + (((u1 + 0) ^ q) & 15) * 8);
      uint2 hi1 = *(const uint2*)(prow + (((u1 + 1) ^ q) & 15) * 8);
      bf1.u = uint4{lo1.x, lo1.y, hi1.x, hi1.y};
    }

    // ---- O^T += V^T·P^T (two k-halves per d-tile) ----
#pragma unroll
    for (int dt = 0; dt < 8; ++dt) {
      o[dt] = __builtin_amdgcn_mfma_f32_16x16x32_bf16(vf0[dt].v, bf0.v, o[dt], 0, 0, 0);
      o[dt] = __builtin_amdgcn_mfma_f32_16x16x32_bf16(vf1[dt].v, bf1.v, o[dt], 0, 0, 0);
    }
  }

  // ---- epilogue: direct store (per-wave transpose is register-local):
  //      out[qrow][dt*16+g*4+j] = o[dt][j]*invl + x2[...] — 64B segments ----
  const float invl = 2.0f / l_run;   // 1/(1-p) / l
  const float* X2r = X2 + (size_t)qrow * Dc;
  float* outr = outp + (size_t)qrow * Dc;
#pragma unroll
  for (int dt = 0; dt < 8; ++dt) {
    int d = dt * 16 + g * 4;
    float4 xv = *(const float4*)&X2r[d];
    *(float4*)&outr[d] = float4{o[dt][0] * invl + xv.x, o[dt][1] * invl + xv.y,
                                o[dt][2] * invl + xv.z, o[dt][3] * invl + xv.w};
  }
}

extern "C" void kernel_launch(void* const* d_in, const int* in_sizes, int n_in,
                              void* d_out, int out_size, void* d_ws, size_t ws_size,
                              hipStream_t stream) {
  const float* x1 = (const float*)d_in[0];
  const float* x2 = (const float*)d_in[1];
  const float* x3 = (const float*)d_in[2];
  float* out = (float*)d_out;
  const size_t PREP = (size_t)2048 * 512 * 16;   // 16.78 MB per bf16 image
  uint4* Kb = (uint4*)d_ws;
  uint4* Vtg = (uint4*)((char*)d_ws + PREP);
  prepack<<<2048, 256, 0, stream>>>(x1, x2, Kb, Vtg);
  attn12<<<1024, 256, 0, stream>>>(Kb, Vtg, x1, x2, x3, out);
}

// Round 11
// 377.597 us; speedup vs baseline: 2.3648x; 2.3648x over previous
//
#include <hip/hip_runtime.h>
#include <math.h>

// Model_39676907887961: out = dropout(softmax(x1@x2^T / x3)) @ x1 + x2
// B=2 H=16 S=2048 D=128. Round 17: champion (r9, 398us = attn 338 + prepack
// 60) + three proven micro-opts. r15/r16's direct-global structure is dead:
// FETCH 1.26GB unchanged under XCD swizzle -> L2-sharing premise falsified.
// System accounting: conserved VALU wall ~267us (tf ~220 + attn-other ~47)
// at ~78% issue efficiency == r9's 338. This round cuts issue work + serial
// overhead on the champion:
//   (1) trimmed tf_o0 (x1-tail dead-coded, proven r10-r14): -6% tf ops;
//   (2) softmax-denominator shfl-reduce deferred to epilogue (sum of sums
//       == reduce of sum; 64 ds_swizzle -> 2);
//   (3) direct epilogue store (proven r15/r16): no Os overlay, -2 barriers.
// Everything else byte-identical to r9: BK=64 single-buffer, 2 barriers/iter,
// tf between DMA-issue and barrier-B (drain cover), P same-wave exchange.
// Mask semantics (verified r9-r16): keep iff MSB(o0)==0 of
// threefry2x32(key=(0,42), ctr=(0,f)), f = row*2048 + t*64 + h2*16 + g*4 + i.

constexpr int Sc = 2048, Dc = 128;
constexpr int NT = 32;                     // 32 tiles of BK=64 (2x 32-key images)
constexpr int VOFF = 16384;                // V region in LDS
constexpr int POFF = 32768;                // P region: 4 waves x 16 rows x 128 B

typedef short bf16x8 __attribute__((ext_vector_type(8)));
typedef float f32x4 __attribute__((ext_vector_type(4)));
union U8 { uint4 u; bf16x8 v; };

__device__ __forceinline__ unsigned rotl(unsigned x, int r) {
  return __builtin_amdgcn_alignbit(x, x, 32 - r);   // rotl(x,r) = rotr(x,32-r)
}

// JAX Threefry-2x32, key=(0,42), ctr=(0,idx): o0 only (x1-tail dead-coded).
__device__ __forceinline__ unsigned tf_o0(unsigned x1) {
  const unsigned ks1 = 42u;
  const unsigned ks2 = 0x1BD11BDAu ^ 42u;  // ks0 = 0
  unsigned x0 = 0u; x1 += ks1;
#define TFR(r) { x0 += x1; x1 = rotl(x1, r); x1 ^= x0; }
  TFR(13) TFR(15) TFR(26) TFR(6)
  x0 += ks1; x1 += ks2 + 1u;
  TFR(17) TFR(29) TFR(16) TFR(24)
  x0 += ks2; x1 += 0u + 2u;
  TFR(13) TFR(15) TFR(26) TFR(6)
  x1 += ks1 + 3u;                          // x0 += ks0 (= 0)
  TFR(17) TFR(29) TFR(16) TFR(24)
  x0 += ks1; x1 += ks2 + 4u;
  TFR(13) TFR(15) TFR(26)
  x0 += x1;                                // final TFR(6): x1 update is dead
  x0 += ks2;                               // o0
#undef TFR
  return x0;
}

// keep iff MSB(o0)==0 -> full-width 0xFFFFFFFF / 0
__device__ __forceinline__ unsigned keepmask(unsigned idx) {
  return (unsigned)(((int)~tf_o0(idx)) >> 31);
}

// pack two f32 -> bf16 pair (round-half-up via +0x8000, then v_perm)
__device__ __forceinline__ unsigned pk2rn(float a, float b) {
  return __builtin_amdgcn_perm(__float_as_uint(b) + 0x8000u,
                               __float_as_uint(a) + 0x8000u, 0x07060302u);
}

// halfword-combine two full-width masks: lo16 from ma, hi16 from mb
__device__ __forceinline__ unsigned hw2(unsigned ma, unsigned mb) {
  return __builtin_amdgcn_perm(mb, ma, 0x05040100u);
}

__device__ __forceinline__ void gload16(const void* g, void* l) {
  __builtin_amdgcn_global_load_lds(
      (const __attribute__((address_space(1))) void*)g,
      (__attribute__((address_space(3))) void*)l, 16, 0, 0);
}

// 8 halfword-pair keep-masks for one 64-key tile row-slice
__device__ __forceinline__ void masks8(unsigned ib, unsigned km[8]) {
#pragma unroll
  for (int h2 = 0; h2 < 4; ++h2) {
    unsigned a0 = keepmask(ib + h2 * 16 + 0), a1 = keepmask(ib + h2 * 16 + 1);
    unsigned a2 = keepmask(ib + h2 * 16 + 2), a3 = keepmask(ib + h2 * 16 + 3);
    km[h2 * 2 + 0] = hw2(a0, a1);
    km[h2 * 2 + 1] = hw2(a2, a3);
  }
}

// ---------------- pre-pass (r5, proven): fragment-linear bf16 images --------
// Per 32-key tile (tile index = bh*64 + tt):
//  K unit u = (mt*4+c)*64 + lane : K[mt*16+(lane&15)][c*32+(lane>>4)*8 .. +7]
//  V unit u = dt*64 + lane       : V[(lane>>4)*8+2p(+1)][dt*16+(lane&15)] pairs
__global__ __launch_bounds__(256)
void prepack(const float* __restrict__ x1, const float* __restrict__ x2,
             uint4* __restrict__ Kb, uint4* __restrict__ Vt) {
  __shared__ ushort Kl[32 * 136];
  __shared__ ushort Vl[32 * 136];
  const int tid = threadIdx.x;
  const size_t tile = blockIdx.x;            // 0..2047
  const float4* ks = (const float4*)(x2 + tile * 4096);
  const float4* vs = (const float4*)(x1 + tile * 4096);
#pragma unroll
  for (int it = 0; it < 4; ++it) {
    int f = it * 256 + tid;
    int row = f >> 5, c4 = f & 31;
    float4 kv = ks[f];
    float4 vv = vs[f];
    *(uint2*)&Kl[row * 136 + c4 * 4] = uint2{pk2rn(kv.x, kv.y), pk2rn(kv.z, kv.w)};
    *(uint2*)&Vl[row * 136 + c4 * 4] = uint2{pk2rn(vv.x, vv.y), pk2rn(vv.z, vv.w)};
  }
  __syncthreads();
#pragma unroll
  for (int it = 0; it < 2; ++it) {
    int u = it * 256 + tid;
    int lane = u & 63, grp = u >> 6;
    int mt = grp >> 2, c = grp & 3, m16 = lane & 15, g = lane >> 4;
    Kb[tile * 512 + u] = *(const uint4*)&Kl[(mt * 16 + m16) * 136 + c * 32 + g * 8];
  }
#pragma unroll
  for (int it = 0; it < 2; ++it) {
    int u = it * 256 + tid;
    int lane = u & 63, dt = u >> 6, m16 = lane & 15, g = lane >> 4;
    int d = dt * 16 + m16, k0 = g * 8;
    unsigned w[4];
#pragma unroll
    for (int p = 0; p < 4; ++p) {
      unsigned lo = Vl[(k0 + 2 * p) * 136 + d];
      unsigned hi = Vl[(k0 + 2 * p + 1) * 136 + d];
      w[p] = lo | (hi << 16);
    }
    Vt[tile * 512 + u] = uint4{w[0], w[1], w[2], w[3]};
  }
}

// ---------------- main kernel ----------------------------------------------
__global__ __launch_bounds__(256, 4)
void attn13(const uint4* __restrict__ Kb, const uint4* __restrict__ Vt,
            const float* __restrict__ x1, const float* __restrict__ x2,
            const float* __restrict__ x3, float* __restrict__ out) {
  __shared__ uint4 smemv[40960 / 16];        // K(16K) V(16K) P(8K)
  char* smem = (char*)smemv;

  const int tid = threadIdx.x, wave = tid >> 6, lane = tid & 63;
  const int g = lane >> 4, q = lane & 15;
  const int blk = blockIdx.x, bh = blk & 31, qt = blk >> 5;

  const float* X1 = x1 + (size_t)bh * (Sc * Dc);
  const float* X2 = x2 + (size_t)bh * (Sc * Dc);
  float* outp = out + (size_t)bh * (Sc * Dc);
  const float cl2 = (1.0f / x3[bh]) * 1.4426950408889634f;   // fold log2(e)

  const int qrow = qt * 64 + wave * 16 + q;
  const unsigned row_base = (unsigned)(bh * Sc + qrow) * (unsigned)Sc;
  char* prow = smem + POFF + wave * 2048 + q * 128;   // this lane's P row

  const size_t tg = (size_t)bh * 64;
  const int off = wave * 1024 + lane * 16;

  // Q B-frags: qf[c] = Q[qrow][c*32 + g*8 .. +7]
  bf16x8 qf[4];
  {
    const float4* qsrc = (const float4*)(X1 + (size_t)qrow * Dc);
#pragma unroll
    for (int c = 0; c < 4; ++c) {
      float4 f0 = qsrc[c * 8 + g * 2], f1 = qsrc[c * 8 + g * 2 + 1];
      U8 cv; cv.u = uint4{pk2rn(f0.x, f0.y), pk2rn(f0.z, f0.w),
                          pk2rn(f1.x, f1.y), pk2rn(f1.z, f1.w)};
      qf[c] = cv.v;
    }
  }

  f32x4 o[8];
#pragma unroll
  for (int i = 0; i < 8; ++i) o[i] = f32x4{0.f, 0.f, 0.f, 0.f};
  float l_part = 0.0f;             // per-lane partial; reduced once in epilogue

  for (int t = 0; t < NT; ++t) {
    __syncthreads();                 // barrier-A: prior tile's readers done
    // ---- issue DMA for tile t (two 32-key subtiles for K and for V) ----
    {
      const char* kg = (const char*)(Kb + (tg + 2 * t) * 512);
      const char* vg = (const char*)(Vt + (tg + 2 * t) * 512);
#pragma unroll
      for (int h = 0; h < 2; ++h) {
        gload16(kg + h * 8192 + off,        smem + h * 8192 + off);
        gload16(kg + h * 8192 + off + 4096, smem + h * 8192 + off + 4096);
        gload16(vg + h * 8192 + off,        smem + VOFF + h * 8192 + off);
        gload16(vg + h * 8192 + off + 4096, smem + VOFF + h * 8192 + off + 4096);
      }
    }
    __builtin_amdgcn_sched_barrier(0);   // keep DMA issue ahead of threefry

    // ---- threefry keep-masks for this tile (data-independent: hides DMA) --
    unsigned km[8];
    masks8(row_base + (unsigned)(t * 64) + (unsigned)(g * 4), km);
    __syncthreads();                 // barrier-B (implicit vmcnt(0): DMA done)

    // ---- S^T = K·Q^T : s[h2][reg] = score(key = h2*16 + g*4 + reg, col q) --
    f32x4 s0 = {}, s1 = {}, s2 = {}, s3 = {};
#pragma unroll
    for (int c = 0; c < 4; ++c) {
      U8 a0; a0.u = *(const uint4*)(smem +        ((0 * 4 + c) * 64 + lane) * 16);
      U8 a1; a1.u = *(const uint4*)(smem +        ((1 * 4 + c) * 64 + lane) * 16);
      U8 a2; a2.u = *(const uint4*)(smem + 8192 + ((0 * 4 + c) * 64 + lane) * 16);
      U8 a3; a3.u = *(const uint4*)(smem + 8192 + ((1 * 4 + c) * 64 + lane) * 16);
      s0 = __builtin_amdgcn_mfma_f32_16x16x32_bf16(a0.v, qf[c], s0, 0, 0, 0);
      s1 = __builtin_amdgcn_mfma_f32_16x16x32_bf16(a1.v, qf[c], s1, 0, 0, 0);
      s2 = __builtin_amdgcn_mfma_f32_16x16x32_bf16(a2.v, qf[c], s2, 0, 0, 0);
      s3 = __builtin_amdgcn_mfma_f32_16x16x32_bf16(a3.v, qf[c], s3, 0, 0, 0);
    }

    // ---- no-max softmax: p = 2^(s*cl2); l excludes dropout.
    //      Cross-lane reduce DEFERRED to epilogue (sum of sums). ----
    float pr[16];
    float ls = 0.0f;
#pragma unroll
    for (int i = 0; i < 4; ++i) { pr[i]      = __builtin_amdgcn_exp2f(s0[i] * cl2); ls += pr[i]; }
#pragma unroll
    for (int i = 0; i < 4; ++i) { pr[4 + i]  = __builtin_amdgcn_exp2f(s1[i] * cl2); ls += pr[4 + i]; }
#pragma unroll
    for (int i = 0; i < 4; ++i) { pr[8 + i]  = __builtin_amdgcn_exp2f(s2[i] * cl2); ls += pr[8 + i]; }
#pragma unroll
    for (int i = 0; i < 4; ++i) { pr[12 + i] = __builtin_amdgcn_exp2f(s3[i] * cl2); ls += pr[12 + i]; }
    l_part += ls;

    // ---- pack + mask + write P units (unit u = (h2>>1)*8+(h2&1)*4+g,
    //      4 bf16 keys each; XOR-swizzled by q, same-wave exchange, no barrier)
#pragma unroll
    for (int h2 = 0; h2 < 4; ++h2) {
      unsigned w0 = pk2rn(pr[h2 * 4 + 0], pr[h2 * 4 + 1]) & km[h2 * 2 + 0];
      unsigned w1 = pk2rn(pr[h2 * 4 + 2], pr[h2 * 4 + 3]) & km[h2 * 2 + 1];
      int u = (h2 >> 1) * 8 + (h2 & 1) * 4 + g;
      *(uint2*)(prow + ((u ^ q) & 15) * 8) = uint2{w0, w1};
    }

    // ---- B-frags for PV from P rows (b64 pairs, swizzle-aware order) ----
    U8 bf0, bf1;
    {
      int u0 = 2 * g;            // kh = 0: keys g*8 .. +7
      uint2 lo0 = *(const uint2*)(prow + (((u0 + 0) ^ q) & 15) * 8);
      uint2 hi0 = *(const uint2*)(prow + (((u0 + 1) ^ q) & 15) * 8);
      bf0.u = uint4{lo0.x, lo0.y, hi0.x, hi0.y};
      int u1 = 8 + 2 * g;        // kh = 1: keys 32 + g*8 .. +7
      uint2 lo1 = *(const uint2*)(prow + (((u1 + 0) ^ q) & 15) * 8);
      uint2 hi1 = *(const uint2*)(prow + (((u1 + 1) ^ q) & 15) * 8);
      bf1.u = uint4{lo1.x, lo1.y, hi1.x, hi1.y};
    }

    // ---- O^T += V^T·P^T (two k-halves per d-tile) ----
#pragma unroll
    for (int dt = 0; dt < 8; ++dt) {
      U8 av0; av0.u = *(const uint4*)(smem + VOFF +        (dt * 64 + lane) * 16);
      U8 av1; av1.u = *(const uint4*)(smem + VOFF + 8192 + (dt * 64 + lane) * 16);
      o[dt] = __builtin_amdgcn_mfma_f32_16x16x32_bf16(av0.v, bf0.v, o[dt], 0, 0, 0);
      o[dt] = __builtin_amdgcn_mfma_f32_16x16x32_bf16(av1.v, bf1.v, o[dt], 0, 0, 0);
    }
  }

  // ---- epilogue: ONE cross-lane reduce, then direct store (r15-proven):
  //      out[qrow][dt*16+g*4+j] = o[dt][j]*invl + x2[qrow][...] ----
  float l_run = l_part;
  l_run += __shfl_xor(l_run, 16);
  l_run += __shfl_xor(l_run, 32);
  const float invl = 2.0f / l_run;   // 1/(1-p) / l
  const float* X2r = X2 + (size_t)qrow * Dc;
  float* outr = outp + (size_t)qrow * Dc;
#pragma unroll
  for (int dt = 0; dt < 8; ++dt) {
    int d = dt * 16 + g * 4;
    float4 xv = *(const float4*)&X2r[d];
    *(float4*)&outr[d] = float4{o[dt][0] * invl + xv.x, o[dt][1] * invl + xv.y,
                                o[dt][2] * invl + xv.z, o[dt][3] * invl + xv.w};
  }
}

extern "C" void kernel_launch(void* const* d_in, const int* in_sizes, int n_in,
                              void* d_out, int out_size, void* d_ws, size_t ws_size,
                              hipStream_t stream) {
  const float* x1 = (const float*)d_in[0];
  const float* x2 = (const float*)d_in[1];
  const float* x3 = (const float*)d_in[2];
  float* out = (float*)d_out;
  const size_t PREP = (size_t)2048 * 512 * 16;   // 16.78 MB per bf16 image
  uint4* Kb = (uint4*)d_ws;
  uint4* Vtg = (uint4*)((char*)d_ws + PREP);
  prepack<<<2048, 256, 0, stream>>>(x1, x2, Kb, Vtg);
  attn13<<<1024, 256, 0, stream>>>(Kb, Vtg, x1, x2, x3, out);
}